// Round 3
// baseline (201.835 us; speedup 1.0000x reference)
//
#include <hip/hip_runtime.h>

#define LSEQ 4096
#define ROWS 2
#define NB (LSEQ / ROWS)   // 2048 blocks -> 8 blocks/CU = 32 waves/CU
#define NT 256

#define IDEAL 6.0f
#define MIN_DIST 3.4f
#define TARGET 9.0f   // 1.5 * IDEAL
#define W_BOND 1.0f
#define W_CLASH 2.0f
#define W_PAIR 0.5f

// ws layout: ws[0]=clash_sum, ws[1]=pair_sum, ws[2]=contact_count (float, exact:
// cmap values are exactly 0.0/1.0 and total count ~167k << 2^24), ws[3]=done ctr (uint)

__global__ void er_init(float* ws) {
    if (threadIdx.x < 4) ws[threadIdx.x] = 0.0f;   // 0 bits == 0.0f == 0u
}

__global__ __launch_bounds__(NT, 6) void er_main(
        const float* __restrict__ coords,
        const float* __restrict__ cmap,
        float* __restrict__ ws,
        float* __restrict__ out) {
    const int t = threadIdx.x;
    const int b = blockIdx.x;
    const int row0 = b * ROWS;
    const int i0 = row0, i1 = row0 + 1;

    // ---- issue the long-pole loads first: both contact rows, 8 x 16B in flight ----
    const float4* crow0 = (const float4*)(cmap + (size_t)i0 * LSEQ);
    const float4* crow1 = (const float4*)(cmap + (size_t)i1 * LSEQ);
    float4 ca[4], cb[4];
#pragma unroll
    for (int k = 0; k < 4; ++k) ca[k] = crow0[t + 256 * k];
#pragma unroll
    for (int k = 0; k < 4; ++k) cb[k] = crow1[t + 256 * k];

    // ---- preload this thread's 16 j-coords (L2-hot after first blocks) ----
    // j = 4*t + 1024*k + q ; float4 index 3t + 768k
    float xj[16], yj[16], zj[16];
    const float4* cp4 = (const float4*)coords;
#pragma unroll
    for (int k = 0; k < 4; ++k) {
        float4 a = cp4[3 * t + 768 * k + 0];
        float4 bb = cp4[3 * t + 768 * k + 1];
        float4 c = cp4[3 * t + 768 * k + 2];
        xj[k * 4 + 0] = a.x;  yj[k * 4 + 0] = a.y;  zj[k * 4 + 0] = a.z;
        xj[k * 4 + 1] = a.w;  yj[k * 4 + 1] = bb.x; zj[k * 4 + 1] = bb.y;
        xj[k * 4 + 2] = bb.z; yj[k * 4 + 2] = bb.w; zj[k * 4 + 2] = c.x;
        xj[k * 4 + 3] = c.y;  yj[k * 4 + 3] = c.z;  zj[k * 4 + 3] = c.w;
    }

    // wave-uniform row coords -> scalar loads
    const float xi0 = coords[3 * i0 + 0], yi0 = coords[3 * i0 + 1], zi0 = coords[3 * i0 + 2];
    const float xi1 = coords[3 * i1 + 0], yi1 = coords[3 * i1 + 1], zi1 = coords[3 * i1 + 2];

    // dual accumulators for FMA-chain ILP
    float cl_a = 0.0f, cl_b = 0.0f;
    float pr_a = 0.0f, pr_b = 0.0f;
    float ct_a = 0.0f, ct_b = 0.0f;

#pragma unroll
    for (int r = 0; r < ROWS; ++r) {
        const int i = (r == 0) ? i0 : i1;
        const float xi = (r == 0) ? xi0 : xi1;
        const float yi = (r == 0) ? yi0 : yi1;
        const float zi = (r == 0) ? zi0 : zi1;
#pragma unroll
        for (int k = 0; k < 4; ++k) {
            const float4 c4 = (r == 0) ? ca[k] : cb[k];
            const float cv[4] = {c4.x, c4.y, c4.z, c4.w};
            const int jbase = 4 * t + 1024 * k;
#pragma unroll
            for (int q = 0; q < 4; ++q) {
                const int j = jbase + q;
                const int idx = k * 4 + q;
                const float dx = xi - xj[idx];
                const float dy = yi - yj[idx];
                const float dz = zi - zj[idx];
                const float d2 = dx * dx + dy * dy + dz * dz;
                const float d = sqrtf(d2) + 1e-8f;
                const int sep = j - i;
                // clash: upper triangle, sep >= 3
                float cl = fmaxf(MIN_DIST - d, 0.0f);
                cl = (sep >= 3) ? cl : 0.0f;
                // pair: contact && |sep| >= 3   (|sep|>=3 <=> (unsigned)(sep+2) > 4)
                const bool contact = cv[q] > 0.5f;
                const bool pg = contact && ((unsigned int)(sep + 2) > 4u);
                const float pd = pg ? (d - TARGET) : 0.0f;
                if (q & 1) {
                    cl_b = fmaf(cl, cl, cl_b);
                    pr_b = fmaf(pd, pd, pr_b);
                    ct_b += cv[q];
                } else {
                    cl_a = fmaf(cl, cl, cl_a);
                    pr_a = fmaf(pd, pd, pr_a);
                    ct_a += cv[q];
                }
            }
        }
    }

    float clash_acc = cl_a + cl_b;
    float pair_acc = pr_a + pr_b;
    float cnt_acc = ct_a + ct_b;

    // 64-lane reduction
#pragma unroll
    for (int off = 32; off > 0; off >>= 1) {
        clash_acc += __shfl_down(clash_acc, off);
        pair_acc  += __shfl_down(pair_acc, off);
        cnt_acc   += __shfl_down(cnt_acc, off);
    }
    __shared__ float s_clash[NT / 64], s_pair[NT / 64], s_cnt[NT / 64];
    __shared__ int s_last;
    const int wave = t >> 6;
    const int lane = t & 63;
    if (lane == 0) { s_clash[wave] = clash_acc; s_pair[wave] = pair_acc; s_cnt[wave] = cnt_acc; }
    __syncthreads();
    if (t == 0) {
        float cs = 0.0f, ps = 0.0f, ns = 0.0f;
#pragma unroll
        for (int w = 0; w < NT / 64; ++w) { cs += s_clash[w]; ps += s_pair[w]; ns += s_cnt[w]; }
        atomicAdd(&ws[0], cs);
        atomicAdd(&ws[1], ps);
        atomicAdd(&ws[2], ns);
        __threadfence();   // release partials before signaling done
        const unsigned int old = atomicAdd((unsigned int*)&ws[3], 1u);
        s_last = (old == (unsigned int)(NB - 1)) ? 1 : 0;
    }
    __syncthreads();

    if (s_last) {
        // ---- last block: bond term + combine (fused finalize) ----
        float bacc = 0.0f;
        for (int s = t; s < LSEQ - 1; s += NT) {
            const float dx = coords[3 * (s + 1) + 0] - coords[3 * s + 0];
            const float dy = coords[3 * (s + 1) + 1] - coords[3 * s + 1];
            const float dz = coords[3 * (s + 1) + 2] - coords[3 * s + 2];
            const float d = sqrtf(dx * dx + dy * dy + dz * dz);
            const float e = d - IDEAL;
            bacc += e * e;
        }
#pragma unroll
        for (int off = 32; off > 0; off >>= 1) bacc += __shfl_down(bacc, off);
        __shared__ float sb[NT / 64];
        if (lane == 0) sb[wave] = bacc;
        __syncthreads();
        if (t == 0) {
            float tb = 0.0f;
#pragma unroll
            for (int w = 0; w < NT / 64; ++w) tb += sb[w];
            __threadfence();   // acquire side
            // device-scope atomic reads (per-XCD L2s are not coherent for plain loads)
            const float tc = atomicAdd(&ws[0], 0.0f);
            const float tp = atomicAdd(&ws[1], 0.0f);
            const float tn = atomicAdd(&ws[2], 0.0f);
            const float e_bond = tb / (float)(LSEQ - 1);
            const float e_clash = tc / (float)LSEQ;
            const float e_pair = tp / fmaxf(tn, 1.0f);
            out[0] = W_BOND * e_bond + W_CLASH * e_clash + W_PAIR * e_pair;
        }
    }
}

extern "C" void kernel_launch(void* const* d_in, const int* in_sizes, int n_in,
                              void* d_out, int out_size, void* d_ws, size_t ws_size,
                              hipStream_t stream) {
    const float* coords = (const float*)d_in[0];
    const float* cmap   = (const float*)d_in[1];
    float* ws  = (float*)d_ws;
    float* out = (float*)d_out;

    hipLaunchKernelGGL(er_init, dim3(1), dim3(64), 0, stream, ws);
    hipLaunchKernelGGL(er_main, dim3(NB), dim3(NT), 0, stream, coords, cmap, ws, out);
}

// Round 4
// 201.620 us; speedup vs baseline: 1.0011x; 1.0011x over previous
//
#include <hip/hip_runtime.h>

#define LSEQ 4096
#define ROWS 2
#define NB (LSEQ / ROWS)   // 2048 blocks
#define NT 256

#define IDEAL 6.0f
#define MIN_DIST 3.4f
#define TARGET 9.0f   // 1.5 * IDEAL
#define W_BOND 1.0f
#define W_CLASH 2.0f
#define W_PAIR 0.5f

// ws layout: ws[0]=clash_sum, ws[1]=pair_sum, ws[2]=contact_count (float, exact:
// cmap values are exactly 0.0/1.0, total ~167k << 2^24), ws[3]=done ctr (uint)

__global__ void er_init(float* ws) {
    if (threadIdx.x < 4) ws[threadIdx.x] = 0.0f;   // 0 bits == 0.0f == 0u
}

// launch_bounds(256,4): 4 waves/EU -> 128-VGPR cap. At (256,6) the allocator
// (85-reg cap) sank the coord preload back into the loop -> latency-bound
// (R3: VGPR=40, VALUBusy 12.7%, 126us). We need ~96 live VGPRs to hold
// xj/yj/zj (48) + 8x cmap float4 (32) + accums.
__global__ __launch_bounds__(NT, 4) void er_main(
        const float* __restrict__ coords,
        const float* __restrict__ cmap,
        float* __restrict__ ws,
        float* __restrict__ out) {
    const int t = threadIdx.x;
    const int b = blockIdx.x;
    const int row0 = b * ROWS;
    const int i0 = row0, i1 = row0 + 1;

    // ---- long-pole loads first: both contact rows, 8 x 16B in flight ----
    const float4* crow0 = (const float4*)(cmap + (size_t)i0 * LSEQ);
    const float4* crow1 = (const float4*)(cmap + (size_t)i1 * LSEQ);
    float4 ca[4], cb[4];
#pragma unroll
    for (int k = 0; k < 4; ++k) ca[k] = crow0[t + 256 * k];
#pragma unroll
    for (int k = 0; k < 4; ++k) cb[k] = crow1[t + 256 * k];

    // ---- preload this thread's 16 j-coords into registers ----
    // j = 4*t + 1024*k + q ; float4 index 3t + 768k
    float xj[16], yj[16], zj[16];
    const float4* cp4 = (const float4*)coords;
#pragma unroll
    for (int k = 0; k < 4; ++k) {
        float4 a = cp4[3 * t + 768 * k + 0];
        float4 bb = cp4[3 * t + 768 * k + 1];
        float4 c = cp4[3 * t + 768 * k + 2];
        xj[k * 4 + 0] = a.x;  yj[k * 4 + 0] = a.y;  zj[k * 4 + 0] = a.z;
        xj[k * 4 + 1] = a.w;  yj[k * 4 + 1] = bb.x; zj[k * 4 + 1] = bb.y;
        xj[k * 4 + 2] = bb.z; yj[k * 4 + 2] = bb.w; zj[k * 4 + 2] = c.x;
        xj[k * 4 + 3] = c.y;  yj[k * 4 + 3] = c.z;  zj[k * 4 + 3] = c.w;
    }

    // wave-uniform row coords -> scalar loads
    const float xi0 = coords[3 * i0 + 0], yi0 = coords[3 * i0 + 1], zi0 = coords[3 * i0 + 2];
    const float xi1 = coords[3 * i1 + 0], yi1 = coords[3 * i1 + 1], zi1 = coords[3 * i1 + 2];

    float cl_a = 0.0f, cl_b = 0.0f;
    float pr_a = 0.0f, pr_b = 0.0f;
    float ct_a = 0.0f, ct_b = 0.0f;

#pragma unroll
    for (int r = 0; r < ROWS; ++r) {
        const int i = (r == 0) ? i0 : i1;
        const float xi = (r == 0) ? xi0 : xi1;
        const float yi = (r == 0) ? yi0 : yi1;
        const float zi = (r == 0) ? zi0 : zi1;
#pragma unroll
        for (int k = 0; k < 4; ++k) {
            const float4 c4 = (r == 0) ? ca[k] : cb[k];
            const float cv[4] = {c4.x, c4.y, c4.z, c4.w};
            const int jbase = 4 * t + 1024 * k;
#pragma unroll
            for (int q = 0; q < 4; ++q) {
                const int j = jbase + q;
                const int idx = k * 4 + q;
                const float dx = xi - xj[idx];
                const float dy = yi - yj[idx];
                const float dz = zi - zj[idx];
                const float d2 = dx * dx + dy * dy + dz * dz;
                const float d = sqrtf(d2) + 1e-8f;
                const int sep = j - i;
                // clash: upper triangle, sep >= 3
                float cl = fmaxf(MIN_DIST - d, 0.0f);
                cl = (sep >= 3) ? cl : 0.0f;
                // pair: contact && |sep| >= 3   (|sep|>=3 <=> (unsigned)(sep+2) > 4)
                const bool contact = cv[q] > 0.5f;
                const bool pg = contact && ((unsigned int)(sep + 2) > 4u);
                const float pd = pg ? (d - TARGET) : 0.0f;
                if (q & 1) {
                    cl_b = fmaf(cl, cl, cl_b);
                    pr_b = fmaf(pd, pd, pr_b);
                    ct_b += cv[q];
                } else {
                    cl_a = fmaf(cl, cl, cl_a);
                    pr_a = fmaf(pd, pd, pr_a);
                    ct_a += cv[q];
                }
            }
        }
    }

    float clash_acc = cl_a + cl_b;
    float pair_acc = pr_a + pr_b;
    float cnt_acc = ct_a + ct_b;

    // 64-lane reduction
#pragma unroll
    for (int off = 32; off > 0; off >>= 1) {
        clash_acc += __shfl_down(clash_acc, off);
        pair_acc  += __shfl_down(pair_acc, off);
        cnt_acc   += __shfl_down(cnt_acc, off);
    }
    __shared__ float s_clash[NT / 64], s_pair[NT / 64], s_cnt[NT / 64];
    __shared__ int s_last;
    const int wave = t >> 6;
    const int lane = t & 63;
    if (lane == 0) { s_clash[wave] = clash_acc; s_pair[wave] = pair_acc; s_cnt[wave] = cnt_acc; }
    __syncthreads();
    if (t == 0) {
        float cs = 0.0f, ps = 0.0f, ns = 0.0f;
#pragma unroll
        for (int w = 0; w < NT / 64; ++w) { cs += s_clash[w]; ps += s_pair[w]; ns += s_cnt[w]; }
        atomicAdd(&ws[0], cs);
        atomicAdd(&ws[1], ps);
        atomicAdd(&ws[2], ns);
        __threadfence();   // release partials before signaling done
        const unsigned int old = atomicAdd((unsigned int*)&ws[3], 1u);
        s_last = (old == (unsigned int)(NB - 1)) ? 1 : 0;
    }
    __syncthreads();

    if (s_last) {
        // ---- last block: bond term + combine (fused finalize) ----
        float bacc = 0.0f;
        for (int s = t; s < LSEQ - 1; s += NT) {
            const float dx = coords[3 * (s + 1) + 0] - coords[3 * s + 0];
            const float dy = coords[3 * (s + 1) + 1] - coords[3 * s + 1];
            const float dz = coords[3 * (s + 1) + 2] - coords[3 * s + 2];
            const float d = sqrtf(dx * dx + dy * dy + dz * dz);
            const float e = d - IDEAL;
            bacc += e * e;
        }
#pragma unroll
        for (int off = 32; off > 0; off >>= 1) bacc += __shfl_down(bacc, off);
        __shared__ float sb[NT / 64];
        if (lane == 0) sb[wave] = bacc;
        __syncthreads();
        if (t == 0) {
            float tb = 0.0f;
#pragma unroll
            for (int w = 0; w < NT / 64; ++w) tb += sb[w];
            __threadfence();   // acquire side
            // device-scope atomic reads (per-XCD L2s not coherent for plain loads)
            const float tc = atomicAdd(&ws[0], 0.0f);
            const float tp = atomicAdd(&ws[1], 0.0f);
            const float tn = atomicAdd(&ws[2], 0.0f);
            const float e_bond = tb / (float)(LSEQ - 1);
            const float e_clash = tc / (float)LSEQ;
            const float e_pair = tp / fmaxf(tn, 1.0f);
            out[0] = W_BOND * e_bond + W_CLASH * e_clash + W_PAIR * e_pair;
        }
    }
}

extern "C" void kernel_launch(void* const* d_in, const int* in_sizes, int n_in,
                              void* d_out, int out_size, void* d_ws, size_t ws_size,
                              hipStream_t stream) {
    const float* coords = (const float*)d_in[0];
    const float* cmap   = (const float*)d_in[1];
    float* ws  = (float*)d_ws;
    float* out = (float*)d_out;

    hipLaunchKernelGGL(er_init, dim3(1), dim3(64), 0, stream, ws);
    hipLaunchKernelGGL(er_main, dim3(NB), dim3(NT), 0, stream, coords, cmap, ws, out);
}

// Round 5
// 200.080 us; speedup vs baseline: 1.0088x; 1.0077x over previous
//
#include <hip/hip_runtime.h>

#define LSEQ 4096
#define ROWS 2
#define NB (LSEQ / ROWS)   // 2048 blocks
#define NT 256

#define IDEAL 6.0f
#define MIN_DIST 3.4f
#define TARGET 9.0f   // 1.5 * IDEAL
#define W_BOND 1.0f
#define W_CLASH 2.0f
#define W_PAIR 0.5f

// ws layout: ws[0]=clash_sum, ws[1]=pair_sum, ws[2]=contact_count (float, exact:
// cmap values are exactly 0.0/1.0, total ~167k << 2^24), ws[3]=done ctr (uint)

__global__ void er_init(float* ws) {
    if (threadIdx.x < 4) ws[threadIdx.x] = 0.0f;   // 0 bits == 0.0f == 0u
}

// R3/R4 lesson: big per-thread arrays (48-float coord preload) get SUNK back
// into the loop by the compiler regardless of __launch_bounds__ (VGPR stuck
// at 40, VALUBusy 11%, 140us). Fix: j-tiled loop with tiny per-iteration
// live set — 3 coord float4 + 2 cmap float4 per tile, nothing for the
// compiler to sink. Coord loads repeat per tile but are L1/L2-hot.
__global__ __launch_bounds__(NT) void er_main(
        const float* __restrict__ coords,
        const float* __restrict__ cmap,
        float* __restrict__ ws,
        float* __restrict__ out) {
    const int t = threadIdx.x;
    const int b = blockIdx.x;
    const int row0 = b * ROWS;
    const int i0 = row0, i1 = row0 + 1;

    const float4* cp4 = (const float4*)coords;
    const float4* crow0 = (const float4*)(cmap + (size_t)i0 * LSEQ);
    const float4* crow1 = (const float4*)(cmap + (size_t)i1 * LSEQ);

    // wave-uniform row coords -> scalar loads
    const float xi0 = coords[3 * i0 + 0], yi0 = coords[3 * i0 + 1], zi0 = coords[3 * i0 + 2];
    const float xi1 = coords[3 * i1 + 0], yi1 = coords[3 * i1 + 1], zi1 = coords[3 * i1 + 2];

    // per-row accumulators (2-way ILP)
    float cl0 = 0.0f, cl1 = 0.0f;
    float pr0 = 0.0f, pr1 = 0.0f;
    float ct0 = 0.0f, ct1 = 0.0f;

#pragma unroll
    for (int k = 0; k < 4; ++k) {
        // ---- per-tile loads: 5 x 16B, issued together ----
        const float4 A = cp4[3 * t + 768 * k + 0];
        const float4 B = cp4[3 * t + 768 * k + 1];
        const float4 C = cp4[3 * t + 768 * k + 2];
        const float4 m0 = crow0[t + 256 * k];
        const float4 m1 = crow1[t + 256 * k];

        // AoS unpack of 4 consecutive j-coords (register renaming, free)
        const float xs[4] = {A.x, A.w, B.z, C.y};
        const float ys[4] = {A.y, B.x, B.w, C.z};
        const float zs[4] = {A.z, B.y, C.x, C.w};
        const float cv0[4] = {m0.x, m0.y, m0.z, m0.w};
        const float cv1[4] = {m1.x, m1.y, m1.z, m1.w};
        const int jbase = 4 * t + 1024 * k;

#pragma unroll
        for (int q = 0; q < 4; ++q) {
            const int j = jbase + q;
            // ---- row 0 ----
            {
                const float dx = xi0 - xs[q];
                const float dy = yi0 - ys[q];
                const float dz = zi0 - zs[q];
                const float d = sqrtf(dx * dx + dy * dy + dz * dz) + 1e-8f;
                const int sep = j - i0;
                float cl = fmaxf(MIN_DIST - d, 0.0f);
                cl = (sep >= 3) ? cl : 0.0f;
                cl0 = fmaf(cl, cl, cl0);
                const bool contact = cv0[q] > 0.5f;
                const bool pg = contact && ((unsigned int)(sep + 2) > 4u);
                const float pd = pg ? (d - TARGET) : 0.0f;
                pr0 = fmaf(pd, pd, pr0);
                ct0 += cv0[q];
            }
            // ---- row 1 ----
            {
                const float dx = xi1 - xs[q];
                const float dy = yi1 - ys[q];
                const float dz = zi1 - zs[q];
                const float d = sqrtf(dx * dx + dy * dy + dz * dz) + 1e-8f;
                const int sep = j - i1;
                float cl = fmaxf(MIN_DIST - d, 0.0f);
                cl = (sep >= 3) ? cl : 0.0f;
                cl1 = fmaf(cl, cl, cl1);
                const bool contact = cv1[q] > 0.5f;
                const bool pg = contact && ((unsigned int)(sep + 2) > 4u);
                const float pd = pg ? (d - TARGET) : 0.0f;
                pr1 = fmaf(pd, pd, pr1);
                ct1 += cv1[q];
            }
        }
    }

    float clash_acc = cl0 + cl1;
    float pair_acc = pr0 + pr1;
    float cnt_acc = ct0 + ct1;

    // 64-lane reduction
#pragma unroll
    for (int off = 32; off > 0; off >>= 1) {
        clash_acc += __shfl_down(clash_acc, off);
        pair_acc  += __shfl_down(pair_acc, off);
        cnt_acc   += __shfl_down(cnt_acc, off);
    }
    __shared__ float s_clash[NT / 64], s_pair[NT / 64], s_cnt[NT / 64];
    __shared__ int s_last;
    const int wave = t >> 6;
    const int lane = t & 63;
    if (lane == 0) { s_clash[wave] = clash_acc; s_pair[wave] = pair_acc; s_cnt[wave] = cnt_acc; }
    __syncthreads();
    if (t == 0) {
        float cs = 0.0f, ps = 0.0f, ns = 0.0f;
#pragma unroll
        for (int w = 0; w < NT / 64; ++w) { cs += s_clash[w]; ps += s_pair[w]; ns += s_cnt[w]; }
        atomicAdd(&ws[0], cs);
        atomicAdd(&ws[1], ps);
        atomicAdd(&ws[2], ns);
        __threadfence();   // release partials before signaling done
        const unsigned int old = atomicAdd((unsigned int*)&ws[3], 1u);
        s_last = (old == (unsigned int)(NB - 1)) ? 1 : 0;
    }
    __syncthreads();

    if (s_last) {
        // ---- last block: bond term + combine (fused finalize) ----
        float bacc = 0.0f;
        for (int s = t; s < LSEQ - 1; s += NT) {
            const float dx = coords[3 * (s + 1) + 0] - coords[3 * s + 0];
            const float dy = coords[3 * (s + 1) + 1] - coords[3 * s + 1];
            const float dz = coords[3 * (s + 1) + 2] - coords[3 * s + 2];
            const float d = sqrtf(dx * dx + dy * dy + dz * dz);
            const float e = d - IDEAL;
            bacc += e * e;
        }
#pragma unroll
        for (int off = 32; off > 0; off >>= 1) bacc += __shfl_down(bacc, off);
        __shared__ float sb[NT / 64];
        if (lane == 0) sb[wave] = bacc;
        __syncthreads();
        if (t == 0) {
            float tb = 0.0f;
#pragma unroll
            for (int w = 0; w < NT / 64; ++w) tb += sb[w];
            __threadfence();   // acquire side
            // device-scope atomic reads (per-XCD L2s not coherent for plain loads)
            const float tc = atomicAdd(&ws[0], 0.0f);
            const float tp = atomicAdd(&ws[1], 0.0f);
            const float tn = atomicAdd(&ws[2], 0.0f);
            const float e_bond = tb / (float)(LSEQ - 1);
            const float e_clash = tc / (float)LSEQ;
            const float e_pair = tp / fmaxf(tn, 1.0f);
            out[0] = W_BOND * e_bond + W_CLASH * e_clash + W_PAIR * e_pair;
        }
    }
}

extern "C" void kernel_launch(void* const* d_in, const int* in_sizes, int n_in,
                              void* d_out, int out_size, void* d_ws, size_t ws_size,
                              hipStream_t stream) {
    const float* coords = (const float*)d_in[0];
    const float* cmap   = (const float*)d_in[1];
    float* ws  = (float*)d_ws;
    float* out = (float*)d_out;

    hipLaunchKernelGGL(er_init, dim3(1), dim3(64), 0, stream, ws);
    hipLaunchKernelGGL(er_main, dim3(NB), dim3(NT), 0, stream, coords, cmap, ws, out);
}

// Round 6
// 106.997 us; speedup vs baseline: 1.8864x; 1.8700x over previous
//
#include <hip/hip_runtime.h>

#define LSEQ 4096
#define ROWS 2
#define NB (LSEQ / ROWS)   // 2048 blocks
#define NT 256

#define IDEAL 6.0f
#define MIN_DIST 3.4f
#define TARGET 9.0f   // 1.5 * IDEAL
#define W_BOND 1.0f
#define W_CLASH 2.0f
#define W_PAIR 0.5f

// R3-R5 post-mortem: the fused last-block finalize required a per-block
// __threadfence(). On gfx950 (non-coherent per-XCD L2s) an agent-scope fence
// is an L2 writeback/invalidate (buffer_wbl2/buffer_inv sc1) -> 2048 blocks
// each nuking their XCD's L2 -> all streaming loads fall to L3 latency.
// Evidence: VALUBusy 26%->12.8% while occupancy ROSE 21%->55%, FETCH_SIZE
// unchanged (L3 absorbs re-reads), loop restructuring (R4/R5) no effect.
// Fix: NO atomics, NO fences. Per-block slot writes; a second tiny kernel
// reduces the slots (kernel boundary = visibility).
//
// ws layout (floats): [0..NB) clash partials, [NB..2NB) pair partials,
//                     [2NB..3NB) contact-count partials (exact: counts < 2^24)

__global__ __launch_bounds__(NT) void er_pair(
        const float* __restrict__ coords,
        const float* __restrict__ cmap,
        float* __restrict__ ws) {
    const int t = threadIdx.x;
    const int b = blockIdx.x;
    const int i0 = b * ROWS, i1 = i0 + 1;

    const float4* cp4 = (const float4*)coords;
    const float4* crow0 = (const float4*)(cmap + (size_t)i0 * LSEQ);
    const float4* crow1 = (const float4*)(cmap + (size_t)i1 * LSEQ);

    // wave-uniform row coords -> scalar loads
    const float xi0 = coords[3 * i0 + 0], yi0 = coords[3 * i0 + 1], zi0 = coords[3 * i0 + 2];
    const float xi1 = coords[3 * i1 + 0], yi1 = coords[3 * i1 + 1], zi1 = coords[3 * i1 + 2];

    float cl0 = 0.0f, cl1 = 0.0f;
    float pr0 = 0.0f, pr1 = 0.0f;
    float ct0 = 0.0f, ct1 = 0.0f;

#pragma unroll
    for (int k = 0; k < 4; ++k) {
        // per-tile loads: 5 x 16B (tiny live set -> nothing for compiler to sink)
        const float4 A = cp4[3 * t + 768 * k + 0];
        const float4 B = cp4[3 * t + 768 * k + 1];
        const float4 C = cp4[3 * t + 768 * k + 2];
        const float4 m0 = crow0[t + 256 * k];
        const float4 m1 = crow1[t + 256 * k];

        const float xs[4] = {A.x, A.w, B.z, C.y};
        const float ys[4] = {A.y, B.x, B.w, C.z};
        const float zs[4] = {A.z, B.y, C.x, C.w};
        const float cv0[4] = {m0.x, m0.y, m0.z, m0.w};
        const float cv1[4] = {m1.x, m1.y, m1.z, m1.w};
        const int jbase = 4 * t + 1024 * k;

#pragma unroll
        for (int q = 0; q < 4; ++q) {
            const int j = jbase + q;
            {   // row 0
                const float dx = xi0 - xs[q];
                const float dy = yi0 - ys[q];
                const float dz = zi0 - zs[q];
                const float d = sqrtf(dx * dx + dy * dy + dz * dz) + 1e-8f;
                const int sep = j - i0;
                float cl = fmaxf(MIN_DIST - d, 0.0f);
                cl = (sep >= 3) ? cl : 0.0f;
                cl0 = fmaf(cl, cl, cl0);
                const bool contact = cv0[q] > 0.5f;
                const bool pg = contact && ((unsigned int)(sep + 2) > 4u);
                const float pd = pg ? (d - TARGET) : 0.0f;
                pr0 = fmaf(pd, pd, pr0);
                ct0 += cv0[q];
            }
            {   // row 1
                const float dx = xi1 - xs[q];
                const float dy = yi1 - ys[q];
                const float dz = zi1 - zs[q];
                const float d = sqrtf(dx * dx + dy * dy + dz * dz) + 1e-8f;
                const int sep = j - i1;
                float cl = fmaxf(MIN_DIST - d, 0.0f);
                cl = (sep >= 3) ? cl : 0.0f;
                cl1 = fmaf(cl, cl, cl1);
                const bool contact = cv1[q] > 0.5f;
                const bool pg = contact && ((unsigned int)(sep + 2) > 4u);
                const float pd = pg ? (d - TARGET) : 0.0f;
                pr1 = fmaf(pd, pd, pr1);
                ct1 += cv1[q];
            }
        }
    }

    float clash_acc = cl0 + cl1;
    float pair_acc = pr0 + pr1;
    float cnt_acc = ct0 + ct1;

#pragma unroll
    for (int off = 32; off > 0; off >>= 1) {
        clash_acc += __shfl_down(clash_acc, off);
        pair_acc  += __shfl_down(pair_acc, off);
        cnt_acc   += __shfl_down(cnt_acc, off);
    }
    __shared__ float s_clash[NT / 64], s_pair[NT / 64], s_cnt[NT / 64];
    const int wave = t >> 6;
    const int lane = t & 63;
    if (lane == 0) { s_clash[wave] = clash_acc; s_pair[wave] = pair_acc; s_cnt[wave] = cnt_acc; }
    __syncthreads();
    if (t == 0) {
        float cs = 0.0f, ps = 0.0f, ns = 0.0f;
#pragma unroll
        for (int w = 0; w < NT / 64; ++w) { cs += s_clash[w]; ps += s_pair[w]; ns += s_cnt[w]; }
        ws[b] = cs;            // slot writes: no atomics, no fences
        ws[NB + b] = ps;
        ws[2 * NB + b] = ns;
    }
}

__global__ __launch_bounds__(NT) void er_finalize(
        const float* __restrict__ coords,
        const float* __restrict__ ws,
        float* __restrict__ out) {
    const int t = threadIdx.x;
    float cs = 0.0f, ps = 0.0f, ns = 0.0f;
    for (int idx = t; idx < NB; idx += NT) {
        cs += ws[idx];
        ps += ws[NB + idx];
        ns += ws[2 * NB + idx];
    }
    // bond term
    float bacc = 0.0f;
    for (int s = t; s < LSEQ - 1; s += NT) {
        const float dx = coords[3 * (s + 1) + 0] - coords[3 * s + 0];
        const float dy = coords[3 * (s + 1) + 1] - coords[3 * s + 1];
        const float dz = coords[3 * (s + 1) + 2] - coords[3 * s + 2];
        const float d = sqrtf(dx * dx + dy * dy + dz * dz);
        const float e = d - IDEAL;
        bacc += e * e;
    }
#pragma unroll
    for (int off = 32; off > 0; off >>= 1) {
        cs += __shfl_down(cs, off);
        ps += __shfl_down(ps, off);
        ns += __shfl_down(ns, off);
        bacc += __shfl_down(bacc, off);
    }
    __shared__ float sc[NT / 64], sp[NT / 64], sn[NT / 64], sb[NT / 64];
    const int wave = t >> 6;
    const int lane = t & 63;
    if (lane == 0) { sc[wave] = cs; sp[wave] = ps; sn[wave] = ns; sb[wave] = bacc; }
    __syncthreads();
    if (t == 0) {
        float tc = 0.0f, tp = 0.0f, tn = 0.0f, tb = 0.0f;
#pragma unroll
        for (int w = 0; w < NT / 64; ++w) { tc += sc[w]; tp += sp[w]; tn += sn[w]; tb += sb[w]; }
        const float e_bond = tb / (float)(LSEQ - 1);
        const float e_clash = tc / (float)LSEQ;
        const float e_pair = tp / fmaxf(tn, 1.0f);
        out[0] = W_BOND * e_bond + W_CLASH * e_clash + W_PAIR * e_pair;
    }
}

extern "C" void kernel_launch(void* const* d_in, const int* in_sizes, int n_in,
                              void* d_out, int out_size, void* d_ws, size_t ws_size,
                              hipStream_t stream) {
    const float* coords = (const float*)d_in[0];
    const float* cmap   = (const float*)d_in[1];
    float* ws  = (float*)d_ws;
    float* out = (float*)d_out;

    hipLaunchKernelGGL(er_pair, dim3(NB), dim3(NT), 0, stream, coords, cmap, ws);
    hipLaunchKernelGGL(er_finalize, dim3(1), dim3(NT), 0, stream, coords, ws, out);
}

// Round 7
// 105.533 us; speedup vs baseline: 1.9125x; 1.0139x over previous
//
#include <hip/hip_runtime.h>

#define LSEQ 4096
#define ROWS 2
#define NB (LSEQ / ROWS)   // 2048 blocks
#define NT 256

#define IDEAL 6.0f
#define MIN_DIST 3.4f
#define TARGET 9.0f   // 1.5 * IDEAL
#define W_BOND 1.0f
#define W_CLASH 2.0f
#define W_PAIR 0.5f

// Session notes baked in:
// - NO atomics/fences in the hot kernel: a device-scope fence on gfx950 is a
//   per-XCD L2 writeback/invalidate; 2048 of them cost ~100us (R3-R5).
//   Slot writes + separate finalize kernel (kernel boundary = visibility).
// - NO big indexed per-thread arrays: compiler sinks them into the loop
//   regardless of __launch_bounds__ (R4: VGPR stuck at 40, 140us).
// - R7: explicit 1-deep software pipeline: issue tile k+1's 5 independent
//   16B loads before computing tile k -> 2x loads in flight per wave to
//   cover L2/L3 latency. Live set ~10 float4 + 6 accs, no arrays.
//
// ws layout (floats): [0..NB) clash partials, [NB..2NB) pair partials,
//                     [2NB..3NB) contact-count partials (exact: cmap is
//                     0.0/1.0 and total count ~167k << 2^24)

__global__ __launch_bounds__(NT) void er_pair(
        const float* __restrict__ coords,
        const float* __restrict__ cmap,
        float* __restrict__ ws) {
    const int t = threadIdx.x;
    const int b = blockIdx.x;
    const int i0 = b * ROWS, i1 = i0 + 1;

    const float4* cp4 = (const float4*)coords;
    const float4* crow0 = (const float4*)(cmap + (size_t)i0 * LSEQ);
    const float4* crow1 = (const float4*)(cmap + (size_t)i1 * LSEQ);

    // wave-uniform row coords -> scalar loads
    const float xi0 = coords[3 * i0 + 0], yi0 = coords[3 * i0 + 1], zi0 = coords[3 * i0 + 2];
    const float xi1 = coords[3 * i1 + 0], yi1 = coords[3 * i1 + 1], zi1 = coords[3 * i1 + 2];

    float cl0 = 0.0f, cl1 = 0.0f;
    float pr0 = 0.0f, pr1 = 0.0f;
    float ct0 = 0.0f, ct1 = 0.0f;

    // ---- prologue: tile 0 loads ----
    float4 A = cp4[3 * t + 0];
    float4 B = cp4[3 * t + 1];
    float4 C = cp4[3 * t + 2];
    float4 m0 = crow0[t];
    float4 m1 = crow1[t];

#pragma unroll
    for (int k = 0; k < 4; ++k) {
        // ---- prefetch tile k+1 (5 independent 16B loads) before compute ----
        float4 An, Bn, Cn, m0n, m1n;
        if (k < 3) {
            An  = cp4[3 * t + 768 * (k + 1) + 0];
            Bn  = cp4[3 * t + 768 * (k + 1) + 1];
            Cn  = cp4[3 * t + 768 * (k + 1) + 2];
            m0n = crow0[t + 256 * (k + 1)];
            m1n = crow1[t + 256 * (k + 1)];
        }

        // AoS unpack of 4 consecutive j-coords (pure register naming)
        const float xs[4] = {A.x, A.w, B.z, C.y};
        const float ys[4] = {A.y, B.x, B.w, C.z};
        const float zs[4] = {A.z, B.y, C.x, C.w};
        const float cv0[4] = {m0.x, m0.y, m0.z, m0.w};
        const float cv1[4] = {m1.x, m1.y, m1.z, m1.w};
        const int jbase = 4 * t + 1024 * k;

#pragma unroll
        for (int q = 0; q < 4; ++q) {
            const int j = jbase + q;
            {   // row 0
                const float dx = xi0 - xs[q];
                const float dy = yi0 - ys[q];
                const float dz = zi0 - zs[q];
                const float d = sqrtf(dx * dx + dy * dy + dz * dz) + 1e-8f;
                const int sep = j - i0;
                float cl = fmaxf(MIN_DIST - d, 0.0f);
                cl = (sep >= 3) ? cl : 0.0f;
                cl0 = fmaf(cl, cl, cl0);
                const bool contact = cv0[q] > 0.5f;
                const bool pg = contact && ((unsigned int)(sep + 2) > 4u);
                const float pd = pg ? (d - TARGET) : 0.0f;
                pr0 = fmaf(pd, pd, pr0);
                ct0 += cv0[q];
            }
            {   // row 1
                const float dx = xi1 - xs[q];
                const float dy = yi1 - ys[q];
                const float dz = zi1 - zs[q];
                const float d = sqrtf(dx * dx + dy * dy + dz * dz) + 1e-8f;
                const int sep = j - i1;
                float cl = fmaxf(MIN_DIST - d, 0.0f);
                cl = (sep >= 3) ? cl : 0.0f;
                cl1 = fmaf(cl, cl, cl1);
                const bool contact = cv1[q] > 0.5f;
                const bool pg = contact && ((unsigned int)(sep + 2) > 4u);
                const float pd = pg ? (d - TARGET) : 0.0f;
                pr1 = fmaf(pd, pd, pr1);
                ct1 += cv1[q];
            }
        }

        // rotate pipeline registers (unrolled -> pure renaming)
        A = An; B = Bn; C = Cn; m0 = m0n; m1 = m1n;
    }

    float clash_acc = cl0 + cl1;
    float pair_acc = pr0 + pr1;
    float cnt_acc = ct0 + ct1;

#pragma unroll
    for (int off = 32; off > 0; off >>= 1) {
        clash_acc += __shfl_down(clash_acc, off);
        pair_acc  += __shfl_down(pair_acc, off);
        cnt_acc   += __shfl_down(cnt_acc, off);
    }
    __shared__ float s_clash[NT / 64], s_pair[NT / 64], s_cnt[NT / 64];
    const int wave = t >> 6;
    const int lane = t & 63;
    if (lane == 0) { s_clash[wave] = clash_acc; s_pair[wave] = pair_acc; s_cnt[wave] = cnt_acc; }
    __syncthreads();
    if (t == 0) {
        float cs = 0.0f, ps = 0.0f, ns = 0.0f;
#pragma unroll
        for (int w = 0; w < NT / 64; ++w) { cs += s_clash[w]; ps += s_pair[w]; ns += s_cnt[w]; }
        ws[b] = cs;            // slot writes: no atomics, no fences
        ws[NB + b] = ps;
        ws[2 * NB + b] = ns;
    }
}

__global__ __launch_bounds__(NT) void er_finalize(
        const float* __restrict__ coords,
        const float* __restrict__ ws,
        float* __restrict__ out) {
    const int t = threadIdx.x;
    float cs = 0.0f, ps = 0.0f, ns = 0.0f;
    for (int idx = t; idx < NB; idx += NT) {
        cs += ws[idx];
        ps += ws[NB + idx];
        ns += ws[2 * NB + idx];
    }
    // bond term
    float bacc = 0.0f;
    for (int s = t; s < LSEQ - 1; s += NT) {
        const float dx = coords[3 * (s + 1) + 0] - coords[3 * s + 0];
        const float dy = coords[3 * (s + 1) + 1] - coords[3 * s + 1];
        const float dz = coords[3 * (s + 1) + 2] - coords[3 * s + 2];
        const float d = sqrtf(dx * dx + dy * dy + dz * dz);
        const float e = d - IDEAL;
        bacc += e * e;
    }
#pragma unroll
    for (int off = 32; off > 0; off >>= 1) {
        cs += __shfl_down(cs, off);
        ps += __shfl_down(ps, off);
        ns += __shfl_down(ns, off);
        bacc += __shfl_down(bacc, off);
    }
    __shared__ float sc[NT / 64], sp[NT / 64], sn[NT / 64], sb[NT / 64];
    const int wave = t >> 6;
    const int lane = t & 63;
    if (lane == 0) { sc[wave] = cs; sp[wave] = ps; sn[wave] = ns; sb[wave] = bacc; }
    __syncthreads();
    if (t == 0) {
        float tc = 0.0f, tp = 0.0f, tn = 0.0f, tb = 0.0f;
#pragma unroll
        for (int w = 0; w < NT / 64; ++w) { tc += sc[w]; tp += sp[w]; tn += sn[w]; tb += sb[w]; }
        const float e_bond = tb / (float)(LSEQ - 1);
        const float e_clash = tc / (float)LSEQ;
        const float e_pair = tp / fmaxf(tn, 1.0f);
        out[0] = W_BOND * e_bond + W_CLASH * e_clash + W_PAIR * e_pair;
    }
}

extern "C" void kernel_launch(void* const* d_in, const int* in_sizes, int n_in,
                              void* d_out, int out_size, void* d_ws, size_t ws_size,
                              hipStream_t stream) {
    const float* coords = (const float*)d_in[0];
    const float* cmap   = (const float*)d_in[1];
    float* ws  = (float*)d_ws;
    float* out = (float*)d_out;

    hipLaunchKernelGGL(er_pair, dim3(NB), dim3(NT), 0, stream, coords, cmap, ws);
    hipLaunchKernelGGL(er_finalize, dim3(1), dim3(NT), 0, stream, coords, ws, out);
}

// Round 8
// 102.832 us; speedup vs baseline: 1.9628x; 1.0263x over previous
//
#include <hip/hip_runtime.h>

#define LSEQ 4096
#define ROWS 2
#define NB (LSEQ / ROWS)   // 2048 blocks
#define NT 256

#define IDEAL 6.0f
#define MIN_DIST 3.4f
#define TARGET 9.0f   // 1.5 * IDEAL
#define W_BOND 1.0f
#define W_CLASH 2.0f
#define W_PAIR 0.5f

// Session rules (hard-won):
// - NO atomics/fences in the hot kernel: device-scope fence on gfx950 =
//   per-XCD L2 writeback/invalidate; 2048 of them cost ~100us (R3-R5).
// - NO big indexed per-thread arrays: compiler sinks them into the loop
//   regardless of __launch_bounds__ (R4).
// - R8: raw v_sqrt_f32 (__builtin_amdgcn_sqrtf) — libm sqrtf's IEEE fixup
//   was ~1/3 of loop VALU; depth-2 pipeline with NAMED float4 slots.
//
// ws layout (floats): [0..NB) clash partials, [NB..2NB) pair partials,
//                     [2NB..3NB) contact-count partials (exact: cmap is
//                     0.0/1.0, total count ~167k << 2^24)

__global__ __launch_bounds__(NT) void er_pair(
        const float* __restrict__ coords,
        const float* __restrict__ cmap,
        float* __restrict__ ws) {
    const int t = threadIdx.x;
    const int b = blockIdx.x;
    const int i0 = b * ROWS, i1 = i0 + 1;

    const float4* cp4 = (const float4*)coords;
    const float4* crow0 = (const float4*)(cmap + (size_t)i0 * LSEQ);
    const float4* crow1 = (const float4*)(cmap + (size_t)i1 * LSEQ);

    // wave-uniform row coords -> scalar loads
    const float xi0 = coords[3 * i0 + 0], yi0 = coords[3 * i0 + 1], zi0 = coords[3 * i0 + 2];
    const float xi1 = coords[3 * i1 + 0], yi1 = coords[3 * i1 + 1], zi1 = coords[3 * i1 + 2];

    float cl0 = 0.0f, cl1 = 0.0f;
    float pr0 = 0.0f, pr1 = 0.0f;
    float ct0 = 0.0f, ct1 = 0.0f;

#define LOAD_TILE(K, A, B, C, M0, M1)                \
    A  = cp4[3 * t + 768 * (K) + 0];                 \
    B  = cp4[3 * t + 768 * (K) + 1];                 \
    C  = cp4[3 * t + 768 * (K) + 2];                 \
    M0 = crow0[t + 256 * (K)];                       \
    M1 = crow1[t + 256 * (K)];

// per-pair cost (post-trim): 3 sub + 3 fma + 1 v_sqrt + 1 sub + 1 max +
// 1 cndmask + 1 fma (clash) + 1 cndmask + 1 mul + 1 fma (pair) + 1 add (cnt)
#define COMP_TILE(K, A, B, C, M0, M1)                                         \
    do {                                                                      \
        const float xs[4] = {A.x, A.w, B.z, C.y};                             \
        const float ys[4] = {A.y, B.x, B.w, C.z};                             \
        const float zs[4] = {A.z, B.y, C.x, C.w};                             \
        const float cv0[4] = {M0.x, M0.y, M0.z, M0.w};                        \
        const float cv1[4] = {M1.x, M1.y, M1.z, M1.w};                        \
        const int jbase = 4 * t + 1024 * (K);                                 \
        _Pragma("unroll")                                                     \
        for (int q = 0; q < 4; ++q) {                                         \
            const int sep0 = jbase + q - i0;  /* sep1 = sep0 - 1 */           \
            {   /* row 0 */                                                   \
                const float dx = xi0 - xs[q];                                 \
                const float dy = yi0 - ys[q];                                 \
                const float dz = zi0 - zs[q];                                 \
                const float d2 = fmaf(dx, dx, fmaf(dy, dy, dz * dz));         \
                const float d = __builtin_amdgcn_sqrtf(d2);                   \
                float cl = fmaxf(MIN_DIST - d, 0.0f);                         \
                cl = (sep0 >= 3) ? cl : 0.0f;                                 \
                cl0 = fmaf(cl, cl, cl0);                                      \
                const float pdm = ((unsigned int)(sep0 + 2) > 4u)             \
                                      ? (d - TARGET) : 0.0f;                  \
                pr0 = fmaf(cv0[q] * pdm, pdm, pr0);                           \
                ct0 += cv0[q];                                                \
            }                                                                 \
            {   /* row 1 */                                                   \
                const float dx = xi1 - xs[q];                                 \
                const float dy = yi1 - ys[q];                                 \
                const float dz = zi1 - zs[q];                                 \
                const float d2 = fmaf(dx, dx, fmaf(dy, dy, dz * dz));         \
                const float d = __builtin_amdgcn_sqrtf(d2);                   \
                float cl = fmaxf(MIN_DIST - d, 0.0f);                         \
                cl = (sep0 >= 4) ? cl : 0.0f;                                 \
                cl1 = fmaf(cl, cl, cl1);                                      \
                const float pdm = ((unsigned int)(sep0 + 1) > 4u)             \
                                      ? (d - TARGET) : 0.0f;                  \
                pr1 = fmaf(cv1[q] * pdm, pdm, pr1);                           \
                ct1 += cv1[q];                                                \
            }                                                                 \
        }                                                                     \
    } while (0)

    // depth-2 software pipeline, fully named slots (no indexed arrays)
    float4 A0, B0, C0, M00, M10;
    float4 A1, B1, C1, M01, M11;
    float4 A2, B2, C2, M02, M12;
    float4 A3, B3, C3, M03, M13;

    LOAD_TILE(0, A0, B0, C0, M00, M10)
    LOAD_TILE(1, A1, B1, C1, M01, M11)
    LOAD_TILE(2, A2, B2, C2, M02, M12)
    COMP_TILE(0, A0, B0, C0, M00, M10);
    LOAD_TILE(3, A3, B3, C3, M03, M13)
    COMP_TILE(1, A1, B1, C1, M01, M11);
    COMP_TILE(2, A2, B2, C2, M02, M12);
    COMP_TILE(3, A3, B3, C3, M03, M13);

#undef LOAD_TILE
#undef COMP_TILE

    float clash_acc = cl0 + cl1;
    float pair_acc = pr0 + pr1;
    float cnt_acc = ct0 + ct1;

#pragma unroll
    for (int off = 32; off > 0; off >>= 1) {
        clash_acc += __shfl_down(clash_acc, off);
        pair_acc  += __shfl_down(pair_acc, off);
        cnt_acc   += __shfl_down(cnt_acc, off);
    }
    __shared__ float s_clash[NT / 64], s_pair[NT / 64], s_cnt[NT / 64];
    const int wave = t >> 6;
    const int lane = t & 63;
    if (lane == 0) { s_clash[wave] = clash_acc; s_pair[wave] = pair_acc; s_cnt[wave] = cnt_acc; }
    __syncthreads();
    if (t == 0) {
        float cs = 0.0f, ps = 0.0f, ns = 0.0f;
#pragma unroll
        for (int w = 0; w < NT / 64; ++w) { cs += s_clash[w]; ps += s_pair[w]; ns += s_cnt[w]; }
        ws[b] = cs;            // slot writes: no atomics, no fences
        ws[NB + b] = ps;
        ws[2 * NB + b] = ns;
    }
}

__global__ __launch_bounds__(NT) void er_finalize(
        const float* __restrict__ coords,
        const float* __restrict__ ws,
        float* __restrict__ out) {
    const int t = threadIdx.x;
    float cs = 0.0f, ps = 0.0f, ns = 0.0f;
    for (int idx = t; idx < NB; idx += NT) {
        cs += ws[idx];
        ps += ws[NB + idx];
        ns += ws[2 * NB + idx];
    }
    // bond term
    float bacc = 0.0f;
    for (int s = t; s < LSEQ - 1; s += NT) {
        const float dx = coords[3 * (s + 1) + 0] - coords[3 * s + 0];
        const float dy = coords[3 * (s + 1) + 1] - coords[3 * s + 1];
        const float dz = coords[3 * (s + 1) + 2] - coords[3 * s + 2];
        const float d = __builtin_amdgcn_sqrtf(fmaf(dx, dx, fmaf(dy, dy, dz * dz)));
        const float e = d - IDEAL;
        bacc += e * e;
    }
#pragma unroll
    for (int off = 32; off > 0; off >>= 1) {
        cs += __shfl_down(cs, off);
        ps += __shfl_down(ps, off);
        ns += __shfl_down(ns, off);
        bacc += __shfl_down(bacc, off);
    }
    __shared__ float sc[NT / 64], sp[NT / 64], sn[NT / 64], sb[NT / 64];
    const int wave = t >> 6;
    const int lane = t & 63;
    if (lane == 0) { sc[wave] = cs; sp[wave] = ps; sn[wave] = ns; sb[wave] = bacc; }
    __syncthreads();
    if (t == 0) {
        float tc = 0.0f, tp = 0.0f, tn = 0.0f, tb = 0.0f;
#pragma unroll
        for (int w = 0; w < NT / 64; ++w) { tc += sc[w]; tp += sp[w]; tn += sn[w]; tb += sb[w]; }
        const float e_bond = tb / (float)(LSEQ - 1);
        const float e_clash = tc / (float)LSEQ;
        const float e_pair = tp / fmaxf(tn, 1.0f);
        out[0] = W_BOND * e_bond + W_CLASH * e_clash + W_PAIR * e_pair;
    }
}

extern "C" void kernel_launch(void* const* d_in, const int* in_sizes, int n_in,
                              void* d_out, int out_size, void* d_ws, size_t ws_size,
                              hipStream_t stream) {
    const float* coords = (const float*)d_in[0];
    const float* cmap   = (const float*)d_in[1];
    float* ws  = (float*)d_ws;
    float* out = (float*)d_out;

    hipLaunchKernelGGL(er_pair, dim3(NB), dim3(NT), 0, stream, coords, cmap, ws);
    hipLaunchKernelGGL(er_finalize, dim3(1), dim3(NT), 0, stream, coords, ws, out);
}

// Round 9
// 101.524 us; speedup vs baseline: 1.9880x; 1.0129x over previous
//
#include <hip/hip_runtime.h>

#define LSEQ 4096
#define ROWS 2
#define NB (LSEQ / ROWS)   // 2048 blocks
#define NT 256

#define IDEAL 6.0f
#define MIN_DIST 3.4f
#define TARGET 9.0f   // 1.5 * IDEAL
#define W_BOND 1.0f
#define W_CLASH 2.0f
#define W_PAIR 0.5f

// Session rules (hard-won):
// - NO atomics/fences in the hot kernel: device-scope fence on gfx950 =
//   per-XCD L2 writeback/invalidate; 2048 of them cost ~100us (R3-R5).
// - NO big indexed per-thread arrays: compiler sinks them into the loop
//   regardless of __launch_bounds__ (R4). Named slots only.
// - Raw v_sqrt_f32 (__builtin_amdgcn_sqrtf): libm fixup was ~1/3 of VALU (R8).
// - R9: ALL 8 cmap float4 loads (the HBM-latency stream) issued up front in
//   named slots; coord loads (L1/L2-hot) on a depth-1 pipeline.
//
// ws layout: float4 per block slot: {clash, pair, count, 0}. Count is exact
// in fp32 (cmap is 0.0/1.0, total ~167k << 2^24).

__global__ __launch_bounds__(NT) void er_pair(
        const float* __restrict__ coords,
        const float* __restrict__ cmap,
        float4* __restrict__ ws) {
    const int t = threadIdx.x;
    const int b = blockIdx.x;
    const int i0 = b * ROWS, i1 = i0 + 1;

    const float4* cp4 = (const float4*)coords;
    const float4* crow0 = (const float4*)(cmap + (size_t)i0 * LSEQ);
    const float4* crow1 = (const float4*)(cmap + (size_t)i1 * LSEQ);

    // ---- issue ALL cmap loads first: 8 x 16B/lane in flight (HBM stream) ----
    float4 M00 = crow0[t +   0], M01 = crow0[t + 256],
           M02 = crow0[t + 512], M03 = crow0[t + 768];
    float4 M10 = crow1[t +   0], M11 = crow1[t + 256],
           M12 = crow1[t + 512], M13 = crow1[t + 768];

    // coord tile 0 (L1/L2-hot after first blocks)
    float4 A = cp4[3 * t + 0];
    float4 B = cp4[3 * t + 1];
    float4 C = cp4[3 * t + 2];

    // wave-uniform row coords -> scalar loads
    const float xi0 = coords[3 * i0 + 0], yi0 = coords[3 * i0 + 1], zi0 = coords[3 * i0 + 2];
    const float xi1 = coords[3 * i1 + 0], yi1 = coords[3 * i1 + 1], zi1 = coords[3 * i1 + 2];

    float cl0 = 0.0f, cl1 = 0.0f;
    float pr0 = 0.0f, pr1 = 0.0f;
    float ct0 = 0.0f, ct1 = 0.0f;

#define COMP_TILE(K, A_, B_, C_, M0, M1)                                      \
    do {                                                                      \
        const float xs[4] = {A_.x, A_.w, B_.z, C_.y};                         \
        const float ys[4] = {A_.y, B_.x, B_.w, C_.z};                         \
        const float zs[4] = {A_.z, B_.y, C_.x, C_.w};                         \
        const float cv0[4] = {M0.x, M0.y, M0.z, M0.w};                        \
        const float cv1[4] = {M1.x, M1.y, M1.z, M1.w};                        \
        const int jbase = 4 * t + 1024 * (K);                                 \
        _Pragma("unroll")                                                     \
        for (int q = 0; q < 4; ++q) {                                         \
            const int sep0 = jbase + q - i0;  /* sep1 = sep0 - 1 */           \
            {   /* row 0 */                                                   \
                const float dx = xi0 - xs[q];                                 \
                const float dy = yi0 - ys[q];                                 \
                const float dz = zi0 - zs[q];                                 \
                const float d2 = fmaf(dx, dx, fmaf(dy, dy, dz * dz));         \
                const float d = __builtin_amdgcn_sqrtf(d2);                   \
                float cl = fmaxf(MIN_DIST - d, 0.0f);                         \
                cl = (sep0 >= 3) ? cl : 0.0f;                                 \
                cl0 = fmaf(cl, cl, cl0);                                      \
                const float pdm = ((unsigned int)(sep0 + 2) > 4u)             \
                                      ? (d - TARGET) : 0.0f;                  \
                pr0 = fmaf(cv0[q] * pdm, pdm, pr0);                           \
                ct0 += cv0[q];                                                \
            }                                                                 \
            {   /* row 1 */                                                   \
                const float dx = xi1 - xs[q];                                 \
                const float dy = yi1 - ys[q];                                 \
                const float dz = zi1 - zs[q];                                 \
                const float d2 = fmaf(dx, dx, fmaf(dy, dy, dz * dz));         \
                const float d = __builtin_amdgcn_sqrtf(d2);                   \
                float cl = fmaxf(MIN_DIST - d, 0.0f);                         \
                cl = (sep0 >= 4) ? cl : 0.0f;                                 \
                cl1 = fmaf(cl, cl, cl1);                                      \
                const float pdm = ((unsigned int)(sep0 + 1) > 4u)             \
                                      ? (d - TARGET) : 0.0f;                  \
                pr1 = fmaf(cv1[q] * pdm, pdm, pr1);                           \
                ct1 += cv1[q];                                                \
            }                                                                 \
        }                                                                     \
    } while (0)

    // depth-1 coord pipeline over 4 tiles; cmap already resident
    float4 An, Bn, Cn;

    An = cp4[3 * t + 768 + 0]; Bn = cp4[3 * t + 768 + 1]; Cn = cp4[3 * t + 768 + 2];
    COMP_TILE(0, A, B, C, M00, M10);
    A = An; B = Bn; C = Cn;

    An = cp4[3 * t + 1536 + 0]; Bn = cp4[3 * t + 1536 + 1]; Cn = cp4[3 * t + 1536 + 2];
    COMP_TILE(1, A, B, C, M01, M11);
    A = An; B = Bn; C = Cn;

    An = cp4[3 * t + 2304 + 0]; Bn = cp4[3 * t + 2304 + 1]; Cn = cp4[3 * t + 2304 + 2];
    COMP_TILE(2, A, B, C, M02, M12);
    A = An; B = Bn; C = Cn;

    COMP_TILE(3, A, B, C, M03, M13);

#undef COMP_TILE

    float clash_acc = cl0 + cl1;
    float pair_acc = pr0 + pr1;
    float cnt_acc = ct0 + ct1;

#pragma unroll
    for (int off = 32; off > 0; off >>= 1) {
        clash_acc += __shfl_down(clash_acc, off);
        pair_acc  += __shfl_down(pair_acc, off);
        cnt_acc   += __shfl_down(cnt_acc, off);
    }
    __shared__ float s_clash[NT / 64], s_pair[NT / 64], s_cnt[NT / 64];
    const int wave = t >> 6;
    const int lane = t & 63;
    if (lane == 0) { s_clash[wave] = clash_acc; s_pair[wave] = pair_acc; s_cnt[wave] = cnt_acc; }
    __syncthreads();
    if (t == 0) {
        float cs = 0.0f, ps = 0.0f, ns = 0.0f;
#pragma unroll
        for (int w = 0; w < NT / 64; ++w) { cs += s_clash[w]; ps += s_pair[w]; ns += s_cnt[w]; }
        ws[b] = make_float4(cs, ps, ns, 0.0f);   // one slot write: no atomics/fences
    }
}

__global__ __launch_bounds__(NT) void er_finalize(
        const float* __restrict__ coords,
        const float4* __restrict__ ws,
        float* __restrict__ out) {
    const int t = threadIdx.x;
    float cs = 0.0f, ps = 0.0f, ns = 0.0f;
    for (int idx = t; idx < NB; idx += NT) {
        const float4 v = ws[idx];
        cs += v.x; ps += v.y; ns += v.z;
    }
    // bond term
    float bacc = 0.0f;
    for (int s = t; s < LSEQ - 1; s += NT) {
        const float dx = coords[3 * (s + 1) + 0] - coords[3 * s + 0];
        const float dy = coords[3 * (s + 1) + 1] - coords[3 * s + 1];
        const float dz = coords[3 * (s + 1) + 2] - coords[3 * s + 2];
        const float d = __builtin_amdgcn_sqrtf(fmaf(dx, dx, fmaf(dy, dy, dz * dz)));
        const float e = d - IDEAL;
        bacc += e * e;
    }
#pragma unroll
    for (int off = 32; off > 0; off >>= 1) {
        cs += __shfl_down(cs, off);
        ps += __shfl_down(ps, off);
        ns += __shfl_down(ns, off);
        bacc += __shfl_down(bacc, off);
    }
    __shared__ float sc[NT / 64], sp[NT / 64], sn[NT / 64], sb[NT / 64];
    const int wave = t >> 6;
    const int lane = t & 63;
    if (lane == 0) { sc[wave] = cs; sp[wave] = ps; sn[wave] = ns; sb[wave] = bacc; }
    __syncthreads();
    if (t == 0) {
        float tc = 0.0f, tp = 0.0f, tn = 0.0f, tb = 0.0f;
#pragma unroll
        for (int w = 0; w < NT / 64; ++w) { tc += sc[w]; tp += sp[w]; tn += sn[w]; tb += sb[w]; }
        const float e_bond = tb / (float)(LSEQ - 1);
        const float e_clash = tc / (float)LSEQ;
        const float e_pair = tp / fmaxf(tn, 1.0f);
        out[0] = W_BOND * e_bond + W_CLASH * e_clash + W_PAIR * e_pair;
    }
}

extern "C" void kernel_launch(void* const* d_in, const int* in_sizes, int n_in,
                              void* d_out, int out_size, void* d_ws, size_t ws_size,
                              hipStream_t stream) {
    const float* coords = (const float*)d_in[0];
    const float* cmap   = (const float*)d_in[1];
    float4* ws = (float4*)d_ws;
    float* out = (float*)d_out;

    hipLaunchKernelGGL(er_pair, dim3(NB), dim3(NT), 0, stream, coords, cmap, ws);
    hipLaunchKernelGGL(er_finalize, dim3(1), dim3(NT), 0, stream, coords, ws, out);
}